// Round 2
// baseline (399.429 us; speedup 1.0000x reference)
//
#include <hip/hip_runtime.h>
#include <math.h>

#define B 32
#define R 5
#define C 100
#define N 101   // C+1
#define H 128
#define E 5
#define NEG_BIG 1e10f

// tanh(x) = 1 - 2/(exp(2x)+1); v_exp + v_rcp based, ~1e-7 rel err
__device__ __forceinline__ float fast_tanh(float x) {
    float e = __expf(2.0f * x);
    return 1.0f - 2.0f * __builtin_amdgcn_rcpf(e + 1.0f);
}

// -------- presence head: softmax over n per (b,c), store presence[b,n,c] --------
__global__ __launch_bounds__(128) void presence_kernel(
        const float* __restrict__ edge, const float* __restrict__ avail,
        const float* __restrict__ w1p, const float* __restrict__ b1p,
        const float* __restrict__ w2p, const float* __restrict__ b2p,
        float* __restrict__ presence) {
    int b = blockIdx.x / C, c = blockIdx.x % C;
    int tid = threadIdx.x;              // 128 threads; thread = node n
    __shared__ float sw1[E * H];
    __shared__ float sb1[H];
    __shared__ float sw2[H];
    __shared__ float red[128];
    for (int t = tid; t < E * H; t += 128) sw1[t] = w1p[t];
    sb1[tid] = b1p[tid];
    sw2[tid] = w2p[tid];
    __syncthreads();

    int n = tid;
    bool active = (n < N);
    float logit = -INFINITY;
    if (active) {
        float d[E];
        const float* ep = edge + ((size_t)(b * C + c) * N + n) * E;
#pragma unroll
        for (int e = 0; e < E; e++) d[e] = ep[e];
        float s = b2p[0];
        for (int h = 0; h < H; h++) {
            float t = sb1[h];
#pragma unroll
            for (int e = 0; e < E; e++) t += d[e] * sw1[e * H + h];
            t = fmaxf(t, 0.0f);
            s += t * sw2[h];
        }
        float h2 = s;  // TAU = 1
        float m = (c == n) ? 0.0f : avail[b * N + n];
        if (n == N - 1) m = 0.0f;
        logit = h2 * m - (1.0f - m) * NEG_BIG;
    }
    // block softmax over the N active lanes
    red[tid] = active ? logit : -INFINITY;
    __syncthreads();
    for (int s2 = 64; s2 > 0; s2 >>= 1) {
        if (tid < s2) red[tid] = fmaxf(red[tid], red[tid + s2]);
        __syncthreads();
    }
    float mx = red[0];
    __syncthreads();
    float ex = active ? __expf(logit - mx) : 0.0f;
    red[tid] = ex;
    __syncthreads();
    for (int s2 = 64; s2 > 0; s2 >>= 1) {
        if (tid < s2) red[tid] += red[tid + s2];
        __syncthreads();
    }
    float denom = red[0];
    if (active) {
        float p = avail[b * N + c] * ex / denom;   // avail[:, :, :-1] factor (index c)
        presence[((size_t)b * N + n) * C + c] = p;
    }
}

// -------- x features -> fx1, and fold iteration 1: u1 = relu(fx1 + bl1) --------
__global__ __launch_bounds__(128) void fx1_kernel(
        const float* __restrict__ ap, const float* __restrict__ ac,
        const float* __restrict__ x_a, const float* __restrict__ x_b,
        const float* __restrict__ coord, const float* __restrict__ avail,
        const float* __restrict__ wx1, const float* __restrict__ bx1,
        const float* __restrict__ bl1,
        float* __restrict__ fx1, float* __restrict__ u1) {
    int b = blockIdx.x / N, n = blockIdx.x % N;
    int h = threadIdx.x;
    __shared__ float xv[16];
    if (h < R) {
        float s = 0.0f;
#pragma unroll
        for (int r = 0; r < R; r++) {
            float a = ap[(b * R + r) * N + n] + ac[(b * R + r) * N + n];
            s += a * x_a[(((size_t)b * R + r) * N + n) * R + h];
        }
        xv[h] = s;
    } else if (h < 10) {
        xv[h] = x_b[(b * N + n) * 5 + (h - 5)];
    } else if (h < 12) {
        xv[h] = coord[(b * N + n) * 2 + (h - 10)];
    } else if (h == 12) {
        xv[12] = avail[b * N + n];
    }
    __syncthreads();
    float s = bx1[h];
#pragma unroll
    for (int k = 0; k < 13; k++) s += xv[k] * wx1[k * H + h];
    size_t o = ((size_t)b * N + n) * H + h;
    fx1[o] = s;
    u1[o] = fmaxf(s + bl1[h], 0.0f);
}

// -------- one message-passing iteration (shared by rounds 1 and 2) --------
// uout[b,n,h] = relu( sum_k l1[b,n,k]*wl[k,h] + bl[h] + fx[b,n,h] )
// l1[b,n,h]   = sum_c presence[b,n,c] * tanh(edge[b,c,n,:]@we + be)[h] * uin[b,c,h]
__global__ __launch_bounds__(128) void iter_kernel(
        const float* __restrict__ presence, const float* __restrict__ edge,
        const float* __restrict__ we, const float* __restrict__ be,
        const float* __restrict__ wl, const float* __restrict__ bl,
        const float* __restrict__ fx, const float* __restrict__ uin,
        float* __restrict__ uout) {
    int b = blockIdx.x / N, n = blockIdx.x % N;
    int h = threadIdx.x;
    __shared__ float pr[C];
    __shared__ float ed[C * E];
    __shared__ float l1s[H];
    for (int t = h; t < C; t += H)
        pr[t] = presence[((size_t)b * N + n) * C + t];
    for (int t = h; t < C * E; t += H) {
        int c = t / E, e = t - c * E;
        ed[t] = edge[(((size_t)b * C + c) * N + n) * E + e];
    }
    float w0 = we[0 * H + h], w1 = we[1 * H + h], w2 = we[2 * H + h],
          w3 = we[3 * H + h], w4 = we[4 * H + h];
    float beh = be[h];
    __syncthreads();

    float acc = 0.0f;
    const float* up = uin + (size_t)b * N * H + h;
    for (int c = 0; c < C; c++) {
        float p = pr[c];
        float arg = beh + ed[c * E + 0] * w0 + ed[c * E + 1] * w1 +
                    ed[c * E + 2] * w2 + ed[c * E + 3] * w3 + ed[c * E + 4] * w4;
        float t = fast_tanh(arg);
        acc += p * t * up[(size_t)c * H];
    }
    l1s[h] = acc;
    __syncthreads();

    float s = bl[h] + fx[((size_t)b * N + n) * H + h];
    for (int k = 0; k < H; k++) s += l1s[k] * wl[k * H + h];
    uout[((size_t)b * N + n) * H + h] = fmaxf(s, 0.0f);
}

// -------- fx2 = u@wx2+bx2, and fold gamma iteration 1: g1 = relu(fx2 + bl2) ---
__global__ __launch_bounds__(128) void fx2_kernel(
        const float* __restrict__ u, const float* __restrict__ wx2,
        const float* __restrict__ bx2, const float* __restrict__ bl2,
        float* __restrict__ fx2, float* __restrict__ g1) {
    int b = blockIdx.x / N, n = blockIdx.x % N;
    int h = threadIdx.x;
    __shared__ float uv[H];
    uv[h] = u[((size_t)b * N + n) * H + h];
    __syncthreads();
    float s = bx2[h];
    for (int k = 0; k < H; k++) s += uv[k] * wx2[k * H + h];
    size_t o = ((size_t)b * N + n) * H + h;
    fx2[o] = s;
    g1[o] = fmaxf(s + bl2[h], 0.0f);
}

// -------- Q[b] = sum_h (sum_n gamma[b,n,h]*avail[b,n]) * wQ[h] ----------------
__global__ __launch_bounds__(128) void final_kernel(
        const float* __restrict__ gamma, const float* __restrict__ avail,
        const float* __restrict__ wQ, float* __restrict__ out) {
    int b = blockIdx.x;
    int h = threadIdx.x;
    float s = 0.0f;
    for (int n = 0; n < N; n++)
        s += gamma[((size_t)b * N + n) * H + h] * avail[b * N + n];
    s *= wQ[h];
    __shared__ float red[H];
    red[h] = s;
    __syncthreads();
    for (int st = 64; st > 0; st >>= 1) {
        if (h < st) red[h] += red[h + st];
        __syncthreads();
    }
    if (h == 0) out[b] = red[0];
}

extern "C" void kernel_launch(void* const* d_in, const int* in_sizes, int n_in,
                              void* d_out, int out_size, void* d_ws, size_t ws_size,
                              hipStream_t stream) {
    const float* ap    = (const float*)d_in[0];   // assignment_prev [B,R,N]
    const float* ac    = (const float*)d_in[1];   // action          [B,R,N]
    const float* x_a   = (const float*)d_in[2];   // [B,R,N,R]
    const float* x_b   = (const float*)d_in[3];   // [B,N,5]
    const float* coord = (const float*)d_in[4];   // [B,N,2]
    const float* edge  = (const float*)d_in[5];   // [B,C,N,E]
    const float* avail = (const float*)d_in[6];   // [B,1,N]
    const float* w1p = (const float*)d_in[7];
    const float* b1p = (const float*)d_in[8];
    const float* w2p = (const float*)d_in[9];
    const float* b2p = (const float*)d_in[10];
    const float* wx1 = (const float*)d_in[11];
    const float* bx1 = (const float*)d_in[12];
    const float* we1 = (const float*)d_in[13];
    const float* be1 = (const float*)d_in[14];
    const float* wl1 = (const float*)d_in[15];
    const float* bl1 = (const float*)d_in[16];
    const float* wx2 = (const float*)d_in[17];
    const float* bx2 = (const float*)d_in[18];
    const float* we2 = (const float*)d_in[19];
    const float* be2 = (const float*)d_in[20];
    const float* wl2 = (const float*)d_in[21];
    const float* bl2 = (const float*)d_in[22];
    const float* wQ  = (const float*)d_in[23];
    float* out = (float*)d_out;

    // workspace layout (floats): presence | fx1 | fx2 | bufA | bufB  (~7.9 MB)
    float* w = (float*)d_ws;
    float* presence = w;                               // B*N*C
    float* fx1 = presence + (size_t)B * N * C;         // B*N*H
    float* fx2 = fx1 + (size_t)B * N * H;
    float* bufA = fx2 + (size_t)B * N * H;
    float* bufB = bufA + (size_t)B * N * H;

    presence_kernel<<<B * C, 128, 0, stream>>>(edge, avail, w1p, b1p, w2p, b2p, presence);
    // round 1: u1 = relu(fx1 + bl1) folded (u0 == 0)
    fx1_kernel<<<B * N, 128, 0, stream>>>(ap, ac, x_a, x_b, coord, avail,
                                          wx1, bx1, bl1, fx1, bufA);
    // 4 remaining round-1 iterations: A->B->A->B->A
    iter_kernel<<<B * N, 128, 0, stream>>>(presence, edge, we1, be1, wl1, bl1, fx1, bufA, bufB);
    iter_kernel<<<B * N, 128, 0, stream>>>(presence, edge, we1, be1, wl1, bl1, fx1, bufB, bufA);
    iter_kernel<<<B * N, 128, 0, stream>>>(presence, edge, we1, be1, wl1, bl1, fx1, bufA, bufB);
    iter_kernel<<<B * N, 128, 0, stream>>>(presence, edge, we1, be1, wl1, bl1, fx1, bufB, bufA);
    // round 2: fx2 from final u (bufA); g1 = relu(fx2 + bl2) into bufB
    fx2_kernel<<<B * N, 128, 0, stream>>>(bufA, wx2, bx2, bl2, fx2, bufB);
    // 4 remaining round-2 iterations: B->A->B->A->B
    iter_kernel<<<B * N, 128, 0, stream>>>(presence, edge, we2, be2, wl2, bl2, fx2, bufB, bufA);
    iter_kernel<<<B * N, 128, 0, stream>>>(presence, edge, we2, be2, wl2, bl2, fx2, bufA, bufB);
    iter_kernel<<<B * N, 128, 0, stream>>>(presence, edge, we2, be2, wl2, bl2, fx2, bufB, bufA);
    iter_kernel<<<B * N, 128, 0, stream>>>(presence, edge, we2, be2, wl2, bl2, fx2, bufA, bufB);
    // final reduction from bufB
    final_kernel<<<B, 128, 0, stream>>>(bufB, avail, wQ, out);
}